// Round 1
// baseline (666.139 us; speedup 1.0000x reference)
//
#include <hip/hip_runtime.h>
#include <math.h>

#define IN_CH 16
#define HC1 128   // H1*C1
#define NH1 4
#define C2 32
#define HID 64
#define NEG 0.2f
#define SCAN_B 256

// ---- CSR build ----
__global__ void k_deg(const int* __restrict__ ei, int E, int N, int* __restrict__ deg) {
    int i = blockIdx.x * blockDim.x + threadIdx.x;
    int M = E + N;
    if (i >= M) return;
    int dst = (i < E) ? ei[E + i] : (i - E);
    atomicAdd(&deg[dst], 1);
}

__global__ void k_scan1(const int* __restrict__ deg, int N, int* __restrict__ tmp, int* __restrict__ bsum) {
    __shared__ int s[SCAN_B];
    int i = blockIdx.x * SCAN_B + threadIdx.x;
    int v = (i < N) ? deg[i] : 0;
    s[threadIdx.x] = v;
    __syncthreads();
    for (int o = 1; o < SCAN_B; o <<= 1) {
        int add = (threadIdx.x >= o) ? s[threadIdx.x - o] : 0;
        __syncthreads();
        s[threadIdx.x] += add;
        __syncthreads();
    }
    if (i < N) tmp[i] = s[threadIdx.x];
    if (threadIdx.x == SCAN_B - 1) bsum[blockIdx.x] = s[SCAN_B - 1];
}

__global__ void k_scan2(const int* __restrict__ bsum, int nb, int* __restrict__ boff,
                        int* __restrict__ offsets, int N) {
    __shared__ int s[1024];
    int t = threadIdx.x;
    int v = (t < nb) ? bsum[t] : 0;
    s[t] = v;
    __syncthreads();
    for (int o = 1; o < 1024; o <<= 1) {
        int add = (t >= o) ? s[t - o] : 0;
        __syncthreads();
        s[t] += add;
        __syncthreads();
    }
    if (t < nb) boff[t] = s[t] - v;          // exclusive block offsets
    if (t == nb - 1) offsets[N] = s[t];      // total M
}

__global__ void k_scan3(const int* __restrict__ deg, const int* __restrict__ tmp,
                        const int* __restrict__ boff, int N,
                        int* __restrict__ offsets, int* __restrict__ cursor) {
    int i = blockIdx.x * SCAN_B + threadIdx.x;
    if (i >= N) return;
    int excl = tmp[i] - deg[i] + boff[blockIdx.x];
    offsets[i] = excl;
    cursor[i] = excl;
}

__global__ void k_scatter(const int* __restrict__ ei, int E, int N,
                          int* __restrict__ cursor, int* __restrict__ elist) {
    int i = blockIdx.x * blockDim.x + threadIdx.x;
    int M = E + N;
    if (i >= M) return;
    int src, dst;
    if (i < E) { src = ei[i]; dst = ei[E + i]; }
    else       { src = dst = i - E; }
    int pos = atomicAdd(&cursor[dst], 1);
    elist[pos] = src;
}

// ---- GAT1 linear + attention logits: one block (128 thr) per node ----
__global__ void k_lin1(const float* __restrict__ x, const float* __restrict__ W1,
                       const float* __restrict__ att_s, const float* __restrict__ att_d,
                       float* __restrict__ h1, float* __restrict__ as1, float* __restrict__ ad1) {
    __shared__ float xs[IN_CH];
    int n = blockIdx.x;
    int t = threadIdx.x;   // 0..127
    if (t < IN_CH) xs[t] = x[n * IN_CH + t];
    __syncthreads();
    float acc = 0.f;
#pragma unroll
    for (int k = 0; k < IN_CH; ++k) acc += xs[k] * W1[k * HC1 + t];
    h1[n * HC1 + t] = acc;
    float vs = acc * att_s[t];
    float vd = acc * att_d[t];
    for (int o = 16; o > 0; o >>= 1) {
        vs += __shfl_down(vs, o, 32);
        vd += __shfl_down(vd, o, 32);
    }
    if ((t & 31) == 0) {
        as1[n * NH1 + (t >> 5)] = vs;
        ad1[n * NH1 + (t >> 5)] = vd;
    }
}

// ---- GAT1 aggregation: one block (128 thr) per dst node ----
__global__ void k_agg1(const int* __restrict__ offsets, const int* __restrict__ elist,
                       const float* __restrict__ h1, const float* __restrict__ as1,
                       const float* __restrict__ ad1, const float* __restrict__ b1,
                       float* __restrict__ out1) {
    int n = blockIdx.x;
    int t = threadIdx.x;   // 128
    int h = t >> 5;
    int lo = offsets[n], hi = offsets[n + 1];
    float adh = ad1[n * NH1 + h];
    float acc = 0.f, sumw = 0.f;
    for (int e = lo; e < hi; ++e) {
        int s = elist[e];
        float z = as1[s * NH1 + h] + adh;
        float lr = z > 0.f ? z : NEG * z;
        float w = expf(lr);
        sumw += w;
        acc += w * h1[s * HC1 + t];
    }
    float val = acc / (sumw + 1e-16f) + b1[t];
    out1[n * HC1 + t] = val > 0.f ? val : expm1f(val);
}

// ---- GAT2 linear + logits: thread per (node, channel) ----
__global__ void k_lin2(const float* __restrict__ out1, const float* __restrict__ W2,
                       const float* __restrict__ att_s, const float* __restrict__ att_d,
                       int N, float* __restrict__ h2, float* __restrict__ as2, float* __restrict__ ad2) {
    int idx = blockIdx.x * blockDim.x + threadIdx.x;
    if (idx >= N * C2) return;
    int n = idx >> 5;
    int c = idx & 31;
    const float* row = out1 + n * HC1;
    float acc = 0.f;
#pragma unroll 8
    for (int k = 0; k < HC1; ++k) acc += row[k] * W2[k * C2 + c];
    h2[idx] = acc;
    float vs = acc * att_s[c];
    float vd = acc * att_d[c];
    for (int o = 16; o > 0; o >>= 1) {
        vs += __shfl_down(vs, o, 32);
        vd += __shfl_down(vd, o, 32);
    }
    if (c == 0) { as2[n] = vs; ad2[n] = vd; }
}

// ---- GAT2 aggregation: 2 nodes per 64-thread block ----
__global__ void k_agg2(const int* __restrict__ offsets, const int* __restrict__ elist,
                       const float* __restrict__ h2, const float* __restrict__ as2,
                       const float* __restrict__ ad2, const float* __restrict__ b2,
                       int N, float* __restrict__ out2) {
    int t = threadIdx.x;
    int n = blockIdx.x * 2 + (t >> 5);
    int c = t & 31;
    if (n >= N) return;
    int lo = offsets[n], hi = offsets[n + 1];
    float adh = ad2[n];
    float acc = 0.f, sumw = 0.f;
    for (int e = lo; e < hi; ++e) {
        int s = elist[e];
        float z = as2[s] + adh;
        float lr = z > 0.f ? z : NEG * z;
        float w = expf(lr);
        sumw += w;
        acc += w * h2[s * C2 + c];
    }
    float val = acc / (sumw + 1e-16f) + b2[c];
    out2[n * C2 + c] = val > 0.f ? val : expm1f(val);
}

// ---- mean-pool per graph + MLP head: one block (256 thr) per graph ----
__global__ void k_pool(const float* __restrict__ out2, const int* __restrict__ batch,
                       int N, const float* __restrict__ Wh1, const float* __restrict__ bh1,
                       const float* __restrict__ Wh2, const float* __restrict__ bh2,
                       float* __restrict__ out) {
    int g = blockIdx.x;
    int t = threadIdx.x;
    __shared__ int sb[2];
    __shared__ float pooled[C2];
    __shared__ float red[256];
    if (t < 2) {
        int target = g + t;
        int lo = 0, hi = N;
        while (lo < hi) { int mid = (lo + hi) >> 1; if (batch[mid] < target) lo = mid + 1; else hi = mid; }
        sb[t] = lo;
    }
    __syncthreads();
    int lo = sb[0], hi = sb[1];
    int c = t & 31, grp = t >> 5;   // 8 node-groups
    float part = 0.f;
    for (int n = lo + grp; n < hi; n += 8) part += out2[n * C2 + c];
    red[t] = part;
    __syncthreads();
    if (t < 128) red[t] += red[t + 128];
    __syncthreads();
    if (t < 64) red[t] += red[t + 64];
    __syncthreads();
    if (t < 32) {
        red[t] += red[t + 32];
        float cnt = (float)(hi - lo);
        pooled[t] = red[t] / fmaxf(cnt, 1.f);
    }
    __syncthreads();
    float hval = 0.f;
    if (t < HID) {
        float a = bh1[t];
#pragma unroll
        for (int cc = 0; cc < C2; ++cc) a += pooled[cc] * Wh1[cc * HID + t];
        hval = fmaxf(a, 0.f) * Wh2[t];
    }
    if (t < 64) {
        for (int o = 32; o > 0; o >>= 1) hval += __shfl_down(hval, o, 64);
        if (t == 0) out[g] = hval + bh2[0];
    }
}

extern "C" void kernel_launch(void* const* d_in, const int* in_sizes, int n_in,
                              void* d_out, int out_size, void* d_ws, size_t ws_size,
                              hipStream_t stream) {
    const float* x    = (const float*)d_in[0];
    const int*   ei   = (const int*)d_in[1];
    const int*   batch= (const int*)d_in[2];
    const float* W1   = (const float*)d_in[3];
    const float* aS1  = (const float*)d_in[4];
    const float* aD1  = (const float*)d_in[5];
    const float* b1   = (const float*)d_in[6];
    const float* W2   = (const float*)d_in[7];
    const float* aS2  = (const float*)d_in[8];
    const float* aD2  = (const float*)d_in[9];
    const float* b2   = (const float*)d_in[10];
    const float* Wh1  = (const float*)d_in[11];
    const float* bh1  = (const float*)d_in[12];
    const float* Wh2  = (const float*)d_in[13];
    const float* bh2  = (const float*)d_in[14];
    float* out = (float*)d_out;

    int N = in_sizes[2];
    int E = in_sizes[1] / 2;
    int M = E + N;
    int G = out_size;
    int nb = (N + SCAN_B - 1) / SCAN_B;

    char* p = (char*)d_ws;
    auto alloc = [&](size_t bytes) -> void* {
        void* r = (void*)p;
        p += (bytes + 255) & ~(size_t)255;
        return r;
    };
    float* h1      = (float*)alloc((size_t)N * HC1 * 4);
    float* out1    = (float*)alloc((size_t)N * HC1 * 4);
    float* as1     = (float*)alloc((size_t)N * NH1 * 4);
    float* ad1     = (float*)alloc((size_t)N * NH1 * 4);
    float* h2      = (float*)alloc((size_t)N * C2 * 4);
    float* as2     = (float*)alloc((size_t)N * 4);
    float* ad2     = (float*)alloc((size_t)N * 4);
    float* out2    = (float*)alloc((size_t)N * C2 * 4);
    int*   deg     = (int*)alloc((size_t)N * 4);
    int*   offsets = (int*)alloc((size_t)(N + 1) * 4);
    int*   cursor  = (int*)alloc((size_t)(N + 1) * 4);
    int*   elist   = (int*)alloc((size_t)M * 4);
    int*   tmp     = (int*)alloc((size_t)N * 4);
    int*   bsum    = (int*)alloc((size_t)nb * 4);
    int*   boff    = (int*)alloc((size_t)nb * 4);

    hipMemsetAsync(deg, 0, (size_t)N * 4, stream);
    k_deg<<<(M + 255) / 256, 256, 0, stream>>>(ei, E, N, deg);
    k_scan1<<<nb, SCAN_B, 0, stream>>>(deg, N, tmp, bsum);
    k_scan2<<<1, 1024, 0, stream>>>(bsum, nb, boff, offsets, N);
    k_scan3<<<nb, SCAN_B, 0, stream>>>(deg, tmp, boff, N, offsets, cursor);
    k_scatter<<<(M + 255) / 256, 256, 0, stream>>>(ei, E, N, cursor, elist);
    k_lin1<<<N, 128, 0, stream>>>(x, W1, aS1, aD1, h1, as1, ad1);
    k_agg1<<<N, 128, 0, stream>>>(offsets, elist, h1, as1, ad1, b1, out1);
    k_lin2<<<(N * C2 + 255) / 256, 256, 0, stream>>>(out1, W2, aS2, aD2, N, h2, as2, ad2);
    k_agg2<<<(N + 1) / 2, 64, 0, stream>>>(offsets, elist, h2, as2, ad2, b2, N, out2);
    k_pool<<<G, 256, 0, stream>>>(out2, batch, N, Wh1, bh1, Wh2, bh2, out);
}

// Round 2
// 566.102 us; speedup vs baseline: 1.1767x; 1.1767x over previous
//
#include <hip/hip_runtime.h>
#include <math.h>

#define IN_CH 16
#define HC1 128   // H1*C1
#define NH1 4
#define C2 32
#define HID 64
#define NEG 0.2f
#define SCAN_B 256

__device__ __forceinline__ float lrelu_exp(float z) {
    float lr = z > 0.f ? z : NEG * z;
    return expf(lr);
}

// ---- CSR build ----
__global__ void k_deg(const int* __restrict__ ei, int E, int N, int* __restrict__ deg) {
    int i = blockIdx.x * blockDim.x + threadIdx.x;
    int M = E + N;
    if (i >= M) return;
    int dst = (i < E) ? ei[E + i] : (i - E);
    atomicAdd(&deg[dst], 1);
}

__global__ void k_scan1(const int* __restrict__ deg, int N, int* __restrict__ tmp, int* __restrict__ bsum) {
    __shared__ int s[SCAN_B];
    int i = blockIdx.x * SCAN_B + threadIdx.x;
    int v = (i < N) ? deg[i] : 0;
    s[threadIdx.x] = v;
    __syncthreads();
    for (int o = 1; o < SCAN_B; o <<= 1) {
        int add = (threadIdx.x >= o) ? s[threadIdx.x - o] : 0;
        __syncthreads();
        s[threadIdx.x] += add;
        __syncthreads();
    }
    if (i < N) tmp[i] = s[threadIdx.x];
    if (threadIdx.x == SCAN_B - 1) bsum[blockIdx.x] = s[SCAN_B - 1];
}

__global__ void k_scan2(const int* __restrict__ bsum, int nb, int* __restrict__ boff,
                        int* __restrict__ offsets, int N) {
    __shared__ int s[1024];
    int t = threadIdx.x;
    int v = (t < nb) ? bsum[t] : 0;
    s[t] = v;
    __syncthreads();
    for (int o = 1; o < 1024; o <<= 1) {
        int add = (t >= o) ? s[t - o] : 0;
        __syncthreads();
        s[t] += add;
        __syncthreads();
    }
    if (t < nb) boff[t] = s[t] - v;
    if (t == nb - 1) offsets[N] = s[t];
}

__global__ void k_scan3(const int* __restrict__ deg, const int* __restrict__ tmp,
                        const int* __restrict__ boff, int N,
                        int* __restrict__ offsets, int* __restrict__ cursor) {
    int i = blockIdx.x * SCAN_B + threadIdx.x;
    if (i >= N) return;
    int excl = tmp[i] - deg[i] + boff[blockIdx.x];
    offsets[i] = excl;
    cursor[i] = excl;
}

// scatter + per-edge GAT1 attention weights (4 heads) in one pass
__global__ void k_scatter_w(const int* __restrict__ ei, int E, int N,
                            int* __restrict__ cursor, int* __restrict__ elist,
                            int* __restrict__ dlist,
                            const float4* __restrict__ as1, const float4* __restrict__ ad1,
                            float4* __restrict__ w1) {
    int i = blockIdx.x * blockDim.x + threadIdx.x;
    int M = E + N;
    if (i >= M) return;
    int src, dst;
    if (i < E) { src = ei[i]; dst = ei[E + i]; }
    else       { src = dst = i - E; }
    int pos = atomicAdd(&cursor[dst], 1);
    elist[pos] = src;
    dlist[pos] = dst;
    float4 zs = as1[src];
    float4 zd = ad1[dst];
    float4 w;
    w.x = lrelu_exp(zs.x + zd.x);
    w.y = lrelu_exp(zs.y + zd.y);
    w.z = lrelu_exp(zs.z + zd.z);
    w.w = lrelu_exp(zs.w + zd.w);
    w1[pos] = w;
}

// ---- GAT1 linear + attention logits: one block (128 thr) per node ----
__global__ void k_lin1(const float* __restrict__ x, const float* __restrict__ W1,
                       const float* __restrict__ att_s, const float* __restrict__ att_d,
                       float* __restrict__ h1, float* __restrict__ as1, float* __restrict__ ad1) {
    __shared__ float xs[IN_CH];
    int n = blockIdx.x;
    int t = threadIdx.x;   // 0..127
    if (t < IN_CH) xs[t] = x[n * IN_CH + t];
    __syncthreads();
    float acc = 0.f;
#pragma unroll
    for (int k = 0; k < IN_CH; ++k) acc += xs[k] * W1[k * HC1 + t];
    h1[n * HC1 + t] = acc;
    float vs = acc * att_s[t];
    float vd = acc * att_d[t];
    for (int o = 16; o > 0; o >>= 1) {
        vs += __shfl_down(vs, o, 32);
        vd += __shfl_down(vd, o, 32);
    }
    if ((t & 31) == 0) {
        as1[n * NH1 + (t >> 5)] = vs;
        ad1[n * NH1 + (t >> 5)] = vd;
    }
}

// ---- GAT1 aggregation: one wave per dst node, float2 per lane ----
__global__ void k_agg1(const int* __restrict__ offsets, const int* __restrict__ elist,
                       const float* __restrict__ w1, const float2* __restrict__ h1,
                       const float* __restrict__ b1, int N, float2* __restrict__ out1) {
    int wave = threadIdx.x >> 6;
    int lane = threadIdx.x & 63;
    int n = blockIdx.x * 4 + wave;
    if (n >= N) return;
    int lo = offsets[n], hi = offsets[n + 1];
    int h = lane >> 4;                     // channel pair 2*lane -> head lane/16
    float ax = 0.f, ay = 0.f, sumw = 0.f;
    for (int e = lo; e < hi; ++e) {
        int s = elist[e];
        float w = w1[(size_t)e * 4 + h];
        float2 v = h1[(size_t)s * 64 + lane];
        sumw += w;
        ax += w * v.x;
        ay += w * v.y;
    }
    float inv = 1.f / (sumw + 1e-16f);
    float2 bv = ((const float2*)b1)[lane];
    float vx = ax * inv + bv.x;
    float vy = ay * inv + bv.y;
    float2 o;
    o.x = vx > 0.f ? vx : expm1f(vx);
    o.y = vy > 0.f ? vy : expm1f(vy);
    out1[(size_t)n * 64 + lane] = o;
}

// ---- GAT2 linear: LDS-tiled GEMM [N,128]x[128,32] + attention logits ----
#define TN 64
__global__ void k_lin2(const float* __restrict__ out1, const float* __restrict__ W2,
                       const float* __restrict__ att_s, const float* __restrict__ att_d,
                       int N, float* __restrict__ h2, float* __restrict__ as2, float* __restrict__ ad2) {
    __shared__ float sx[TN][HC1 + 1];   // +1 pad: kills 16-way bank conflict
    __shared__ float sw[HC1][C2];
    int t = threadIdx.x;  // 256
    int base = blockIdx.x * TN;
    int lim = (N - base) * HC1;  // valid floats in this tile
    for (int i = t * 4; i < HC1 * C2; i += 1024) {
        float4 v = *(const float4*)(W2 + i);
        sw[i >> 5][i & 31] = v.x;
        sw[i >> 5][(i & 31) + 1] = v.y;
        sw[i >> 5][(i & 31) + 2] = v.z;
        sw[i >> 5][(i & 31) + 3] = v.w;
    }
    for (int i = t * 4; i < TN * HC1; i += 1024) {
        float4 v = (i < lim) ? *(const float4*)(out1 + (size_t)base * HC1 + i)
                             : make_float4(0.f, 0.f, 0.f, 0.f);
        int nn = i >> 7, kk = i & 127;
        sx[nn][kk] = v.x; sx[nn][kk + 1] = v.y; sx[nn][kk + 2] = v.z; sx[nn][kk + 3] = v.w;
    }
    __syncthreads();
    int nloc = t >> 2;            // 0..63
    int c0 = (t & 3) * 8;         // 8 channels per thread
    float acc[8];
#pragma unroll
    for (int j = 0; j < 8; ++j) acc[j] = 0.f;
#pragma unroll 4
    for (int k = 0; k < HC1; ++k) {
        float xv = sx[nloc][k];
        float4 wa = *(float4*)&sw[k][c0];
        float4 wb = *(float4*)&sw[k][c0 + 4];
        acc[0] += xv * wa.x; acc[1] += xv * wa.y; acc[2] += xv * wa.z; acc[3] += xv * wa.w;
        acc[4] += xv * wb.x; acc[5] += xv * wb.y; acc[6] += xv * wb.z; acc[7] += xv * wb.w;
    }
    int n = base + nloc;
    if (n < N) {
        *(float4*)(h2 + (size_t)n * C2 + c0) = make_float4(acc[0], acc[1], acc[2], acc[3]);
        *(float4*)(h2 + (size_t)n * C2 + c0 + 4) = make_float4(acc[4], acc[5], acc[6], acc[7]);
        float ps = 0.f, pd = 0.f;
#pragma unroll
        for (int j = 0; j < 8; ++j) {
            ps += acc[j] * att_s[c0 + j];
            pd += acc[j] * att_d[c0 + j];
        }
        ps += __shfl_down(ps, 1, 64); ps += __shfl_down(ps, 2, 64);
        pd += __shfl_down(pd, 1, 64); pd += __shfl_down(pd, 2, 64);
        if ((t & 3) == 0) { as2[n] = ps; ad2[n] = pd; }
    }
}

// per-edge GAT2 weights
__global__ void k_edgew2(const int* __restrict__ elist, const int* __restrict__ dlist,
                         const float* __restrict__ as2, const float* __restrict__ ad2,
                         int M, float* __restrict__ w2e) {
    int i = blockIdx.x * blockDim.x + threadIdx.x;
    if (i >= M) return;
    w2e[i] = lrelu_exp(as2[elist[i]] + ad2[dlist[i]]);
}

// ---- GAT2 aggregation: one wave per dst, two half-waves interleave edges ----
__global__ void k_agg2(const int* __restrict__ offsets, const int* __restrict__ elist,
                       const float* __restrict__ w2e, const float* __restrict__ h2,
                       const float* __restrict__ b2, int N, float* __restrict__ out2) {
    int wave = threadIdx.x >> 6;
    int lane = threadIdx.x & 63;
    int n = blockIdx.x * 4 + wave;
    if (n >= N) return;
    int lo = offsets[n], hi = offsets[n + 1];
    int c = lane & 31, half = lane >> 5;
    float acc = 0.f, sumw = 0.f;
    for (int e = lo + half; e < hi; e += 2) {
        int s = elist[e];
        float w = w2e[e];
        acc += w * h2[(size_t)s * C2 + c];
        sumw += w;
    }
    acc  += __shfl_xor(acc, 32, 64);
    sumw += __shfl_xor(sumw, 32, 64);
    if (half == 0) {
        float val = acc / (sumw + 1e-16f) + b2[c];
        out2[(size_t)n * C2 + c] = val > 0.f ? val : expm1f(val);
    }
}

// ---- mean-pool per graph + MLP head ----
__global__ void k_pool(const float* __restrict__ out2, const int* __restrict__ batch,
                       int N, const float* __restrict__ Wh1, const float* __restrict__ bh1,
                       const float* __restrict__ Wh2, const float* __restrict__ bh2,
                       float* __restrict__ out) {
    int g = blockIdx.x;
    int t = threadIdx.x;
    __shared__ int sb[2];
    __shared__ float pooled[C2];
    __shared__ float red[256];
    if (t < 2) {
        int target = g + t;
        int lo = 0, hi = N;
        while (lo < hi) { int mid = (lo + hi) >> 1; if (batch[mid] < target) lo = mid + 1; else hi = mid; }
        sb[t] = lo;
    }
    __syncthreads();
    int lo = sb[0], hi = sb[1];
    int c = t & 31, grp = t >> 5;
    float part = 0.f;
    for (int n = lo + grp; n < hi; n += 8) part += out2[n * C2 + c];
    red[t] = part;
    __syncthreads();
    if (t < 128) red[t] += red[t + 128];
    __syncthreads();
    if (t < 64) red[t] += red[t + 64];
    __syncthreads();
    if (t < 32) {
        red[t] += red[t + 32];
        float cnt = (float)(hi - lo);
        pooled[t] = red[t] / fmaxf(cnt, 1.f);
    }
    __syncthreads();
    float hval = 0.f;
    if (t < HID) {
        float a = bh1[t];
#pragma unroll
        for (int cc = 0; cc < C2; ++cc) a += pooled[cc] * Wh1[cc * HID + t];
        hval = fmaxf(a, 0.f) * Wh2[t];
    }
    if (t < 64) {
        for (int o = 32; o > 0; o >>= 1) hval += __shfl_down(hval, o, 64);
        if (t == 0) out[g] = hval + bh2[0];
    }
}

extern "C" void kernel_launch(void* const* d_in, const int* in_sizes, int n_in,
                              void* d_out, int out_size, void* d_ws, size_t ws_size,
                              hipStream_t stream) {
    const float* x    = (const float*)d_in[0];
    const int*   ei   = (const int*)d_in[1];
    const int*   batch= (const int*)d_in[2];
    const float* W1   = (const float*)d_in[3];
    const float* aS1  = (const float*)d_in[4];
    const float* aD1  = (const float*)d_in[5];
    const float* b1   = (const float*)d_in[6];
    const float* W2   = (const float*)d_in[7];
    const float* aS2  = (const float*)d_in[8];
    const float* aD2  = (const float*)d_in[9];
    const float* b2   = (const float*)d_in[10];
    const float* Wh1  = (const float*)d_in[11];
    const float* bh1  = (const float*)d_in[12];
    const float* Wh2  = (const float*)d_in[13];
    const float* bh2  = (const float*)d_in[14];
    float* out = (float*)d_out;

    int N = in_sizes[2];
    int E = in_sizes[1] / 2;
    int M = E + N;
    int G = out_size;
    int nb = (N + SCAN_B - 1) / SCAN_B;

    char* p = (char*)d_ws;
    auto alloc = [&](size_t bytes) -> void* {
        void* r = (void*)p;
        p += (bytes + 255) & ~(size_t)255;
        return r;
    };
    float* h1      = (float*)alloc((size_t)N * HC1 * 4);   // reused as nothing; h2 aliases below
    float* out1    = (float*)alloc((size_t)N * HC1 * 4);
    float* as1     = (float*)alloc((size_t)N * NH1 * 4);
    float* ad1     = (float*)alloc((size_t)N * NH1 * 4);
    float* w1      = (float*)alloc((size_t)M * NH1 * 4);   // reused as w2e after k_agg1
    float* as2     = (float*)alloc((size_t)N * 4);
    float* ad2     = (float*)alloc((size_t)N * 4);
    int*   deg     = (int*)alloc((size_t)N * 4);
    int*   offsets = (int*)alloc((size_t)(N + 1) * 4);
    int*   cursor  = (int*)alloc((size_t)(N + 1) * 4);
    int*   elist   = (int*)alloc((size_t)M * 4);
    int*   dlist   = (int*)alloc((size_t)M * 4);
    int*   tmp     = (int*)alloc((size_t)N * 4);
    int*   bsum    = (int*)alloc((size_t)nb * 4);
    int*   boff    = (int*)alloc((size_t)nb * 4);
    float* h2      = h1;        // h1 dead after k_agg1
    float* out2    = out1;      // out1 dead after k_lin2 (k_lin2 consumed it before h2 write? no -
                                // h2 aliases h1, out2 aliases out1: k_agg2 reads h2(=h1), writes out2(=out1). safe.)
    float* w2e     = w1;        // w1 dead after k_agg1

    hipMemsetAsync(deg, 0, (size_t)N * 4, stream);
    k_deg<<<(M + 255) / 256, 256, 0, stream>>>(ei, E, N, deg);
    k_scan1<<<nb, SCAN_B, 0, stream>>>(deg, N, tmp, bsum);
    k_scan2<<<1, 1024, 0, stream>>>(bsum, nb, boff, offsets, N);
    k_scan3<<<nb, SCAN_B, 0, stream>>>(deg, tmp, boff, N, offsets, cursor);
    k_lin1<<<N, 128, 0, stream>>>(x, W1, aS1, aD1, h1, as1, ad1);
    k_scatter_w<<<(M + 255) / 256, 256, 0, stream>>>(ei, E, N, cursor, elist, dlist,
                                                     (const float4*)as1, (const float4*)ad1,
                                                     (float4*)w1);
    k_agg1<<<(N + 3) / 4, 256, 0, stream>>>(offsets, elist, w1, (const float2*)h1, b1, N,
                                            (float2*)out1);
    k_lin2<<<(N + TN - 1) / TN, 256, 0, stream>>>(out1, W2, aS2, aD2, N, h2, as2, ad2);
    k_edgew2<<<(M + 255) / 256, 256, 0, stream>>>(elist, dlist, as2, ad2, M, w2e);
    k_agg2<<<(N + 3) / 4, 256, 0, stream>>>(offsets, elist, w2e, h2, b2, N, out2);
    k_pool<<<G, 256, 0, stream>>>(out2, batch, N, Wh1, bh1, Wh2, bh2, out);
}

// Round 3
// 518.375 us; speedup vs baseline: 1.2851x; 1.0921x over previous
//
#include <hip/hip_runtime.h>
#include <hip/hip_fp16.h>
#include <math.h>

#define IN_CH 16
#define HC1 128   // H1*C1
#define NH1 4
#define C2 32
#define HID 64
#define NEG 0.2f
#define SCAN_B 256

__device__ __forceinline__ float lrelu_exp(float z) {
    float lr = z > 0.f ? z : NEG * z;
    return expf(lr);
}

// ---- CSR build ----
__global__ void k_deg(const int* __restrict__ ei, int E, int N, int* __restrict__ deg) {
    int i = blockIdx.x * blockDim.x + threadIdx.x;
    int M = E + N;
    if (i >= M) return;
    int dst = (i < E) ? ei[E + i] : (i - E);
    atomicAdd(&deg[dst], 1);
}

__global__ void k_scan1(const int* __restrict__ deg, int N, int* __restrict__ tmp, int* __restrict__ bsum) {
    __shared__ int s[SCAN_B];
    int i = blockIdx.x * SCAN_B + threadIdx.x;
    int v = (i < N) ? deg[i] : 0;
    s[threadIdx.x] = v;
    __syncthreads();
    for (int o = 1; o < SCAN_B; o <<= 1) {
        int add = (threadIdx.x >= o) ? s[threadIdx.x - o] : 0;
        __syncthreads();
        s[threadIdx.x] += add;
        __syncthreads();
    }
    if (i < N) tmp[i] = s[threadIdx.x];
    if (threadIdx.x == SCAN_B - 1) bsum[blockIdx.x] = s[SCAN_B - 1];
}

__global__ void k_scan2(const int* __restrict__ bsum, int nb, int* __restrict__ boff,
                        int* __restrict__ offsets, int N) {
    __shared__ int s[1024];
    int t = threadIdx.x;
    int v = (t < nb) ? bsum[t] : 0;
    s[t] = v;
    __syncthreads();
    for (int o = 1; o < 1024; o <<= 1) {
        int add = (t >= o) ? s[t - o] : 0;
        __syncthreads();
        s[t] += add;
        __syncthreads();
    }
    if (t < nb) boff[t] = s[t] - v;
    if (t == nb - 1) offsets[N] = s[t];
}

__global__ void k_scan3(const int* __restrict__ deg, const int* __restrict__ tmp,
                        const int* __restrict__ boff, int N,
                        int* __restrict__ offsets, int* __restrict__ cursor) {
    int i = blockIdx.x * SCAN_B + threadIdx.x;
    if (i >= N) return;
    int excl = tmp[i] - deg[i] + boff[blockIdx.x];
    offsets[i] = excl;
    cursor[i] = excl;
}

__global__ void k_scatter(const int* __restrict__ ei, int E, int N,
                          int* __restrict__ cursor, int* __restrict__ elist) {
    int i = blockIdx.x * blockDim.x + threadIdx.x;
    int M = E + N;
    if (i >= M) return;
    int src, dst;
    if (i < E) { src = ei[i]; dst = ei[E + i]; }
    else       { src = dst = i - E; }
    int pos = atomicAdd(&cursor[dst], 1);
    elist[pos] = src;
}

// ---- GAT1 linear + logits: one wave per node, 2 channels/lane ----
__global__ void k_lin1(const float* __restrict__ x, const float2* __restrict__ W1v,
                       const float2* __restrict__ att_s2, const float2* __restrict__ att_d2,
                       int N, __half2* __restrict__ h1h, float* __restrict__ as1, float* __restrict__ ad1) {
    int wave = threadIdx.x >> 6;
    int lane = threadIdx.x & 63;
    int n = blockIdx.x * 4 + wave;
    if (n >= N) return;
    float xv = x[n * IN_CH + (lane & 15)];
    float ax = 0.f, ay = 0.f;
#pragma unroll
    for (int k = 0; k < IN_CH; ++k) {
        float xk = __shfl(xv, k, 16);     // broadcast x[n][k]
        float2 w = W1v[k * 64 + lane];
        ax += xk * w.x;
        ay += xk * w.y;
    }
    h1h[(size_t)n * 64 + lane] = __floats2half2_rn(ax, ay);
    float2 s2 = att_s2[lane], d2 = att_d2[lane];
    float vs = ax * s2.x + ay * s2.y;
    float vd = ax * d2.x + ay * d2.y;
#pragma unroll
    for (int o = 1; o < 16; o <<= 1) {
        vs += __shfl_xor(vs, o, 64);
        vd += __shfl_xor(vd, o, 64);
    }
    if ((lane & 15) == 0) {
        as1[n * NH1 + (lane >> 4)] = vs;
        ad1[n * NH1 + (lane >> 4)] = vd;
    }
}

// ---- GAT1 aggregation: one wave per dst, fp16 gather, weights inline ----
__global__ void k_agg1(const int* __restrict__ offsets, const int* __restrict__ elist,
                       const float* __restrict__ as1, const float* __restrict__ ad1,
                       const __half2* __restrict__ h1h, const float2* __restrict__ b1v,
                       int N, __half2* __restrict__ out1h) {
    int wave = threadIdx.x >> 6;
    int lane = threadIdx.x & 63;
    int n = blockIdx.x * 4 + wave;
    if (n >= N) return;
    int lo = offsets[n], hi = offsets[n + 1];
    int h = lane >> 4;
    float adh = ad1[n * NH1 + h];
    float ax = 0.f, ay = 0.f, sumw = 0.f;
    int e = lo;
    for (; e + 1 < hi; e += 2) {
        int s0 = elist[e], s1 = elist[e + 1];
        float z0 = as1[s0 * NH1 + h];
        float z1 = as1[s1 * NH1 + h];
        __half2 v0h = h1h[(size_t)s0 * 64 + lane];
        __half2 v1h = h1h[(size_t)s1 * 64 + lane];
        float w0 = lrelu_exp(z0 + adh);
        float w1 = lrelu_exp(z1 + adh);
        float2 v0 = __half22float2(v0h);
        float2 v1 = __half22float2(v1h);
        sumw += w0 + w1;
        ax += w0 * v0.x + w1 * v1.x;
        ay += w0 * v0.y + w1 * v1.y;
    }
    if (e < hi) {
        int s0 = elist[e];
        float w0 = lrelu_exp(as1[s0 * NH1 + h] + adh);
        float2 v0 = __half22float2(h1h[(size_t)s0 * 64 + lane]);
        sumw += w0;
        ax += w0 * v0.x;
        ay += w0 * v0.y;
    }
    float inv = 1.f / (sumw + 1e-16f);
    float2 bv = b1v[lane];
    float vx = ax * inv + bv.x;
    float vy = ay * inv + bv.y;
    vx = vx > 0.f ? vx : expm1f(vx);
    vy = vy > 0.f ? vy : expm1f(vy);
    out1h[(size_t)n * 64 + lane] = __floats2half2_rn(vx, vy);
}

// ---- GAT2 linear: LDS-tiled GEMM [N,128](fp16) x [128,32] + logits ----
#define TN 64
__global__ void k_lin2(const __half2* __restrict__ out1h, const float* __restrict__ W2,
                       const float* __restrict__ att_s, const float* __restrict__ att_d,
                       int N, __half2* __restrict__ h2h, float* __restrict__ as2, float* __restrict__ ad2) {
    __shared__ float sx[TN][HC1 + 1];
    __shared__ float sw[HC1][C2];
    int t = threadIdx.x;  // 256
    int base = blockIdx.x * TN;
    int lim = (N - base) * HC1;
    for (int i = t * 4; i < HC1 * C2; i += 1024) {
        float4 v = *(const float4*)(W2 + i);
        sw[i >> 5][i & 31] = v.x;
        sw[i >> 5][(i & 31) + 1] = v.y;
        sw[i >> 5][(i & 31) + 2] = v.z;
        sw[i >> 5][(i & 31) + 3] = v.w;
    }
    for (int i = t * 4; i < TN * HC1; i += 1024) {
        float2 a = make_float2(0.f, 0.f), b = make_float2(0.f, 0.f);
        if (i < lim) {
            size_t idx = ((size_t)base * HC1 + i) >> 1;
            a = __half22float2(out1h[idx]);
            b = __half22float2(out1h[idx + 1]);
        }
        int nn = i >> 7, kk = i & 127;
        sx[nn][kk] = a.x; sx[nn][kk + 1] = a.y; sx[nn][kk + 2] = b.x; sx[nn][kk + 3] = b.y;
    }
    __syncthreads();
    int nloc = t >> 2;
    int c0 = (t & 3) * 8;
    float acc[8];
#pragma unroll
    for (int j = 0; j < 8; ++j) acc[j] = 0.f;
#pragma unroll 4
    for (int k = 0; k < HC1; ++k) {
        float xv = sx[nloc][k];
        float4 wa = *(float4*)&sw[k][c0];
        float4 wb = *(float4*)&sw[k][c0 + 4];
        acc[0] += xv * wa.x; acc[1] += xv * wa.y; acc[2] += xv * wa.z; acc[3] += xv * wa.w;
        acc[4] += xv * wb.x; acc[5] += xv * wb.y; acc[6] += xv * wb.z; acc[7] += xv * wb.w;
    }
    int n = base + nloc;
    if (n < N) {
#pragma unroll
        for (int j = 0; j < 4; ++j)
            h2h[(size_t)n * 16 + (c0 >> 1) + j] = __floats2half2_rn(acc[2 * j], acc[2 * j + 1]);
        float ps = 0.f, pd = 0.f;
#pragma unroll
        for (int j = 0; j < 8; ++j) {
            ps += acc[j] * att_s[c0 + j];
            pd += acc[j] * att_d[c0 + j];
        }
        ps += __shfl_down(ps, 1, 64); ps += __shfl_down(ps, 2, 64);
        pd += __shfl_down(pd, 1, 64); pd += __shfl_down(pd, 2, 64);
        if ((t & 3) == 0) { as2[n] = ps; ad2[n] = pd; }
    }
}

// ---- GAT2 aggregation: one wave per dst, 4 edge-slots of 16 lanes ----
__global__ void k_agg2(const int* __restrict__ offsets, const int* __restrict__ elist,
                       const float* __restrict__ as2, const float* __restrict__ ad2,
                       const __half2* __restrict__ h2h, const float2* __restrict__ b2v,
                       int N, float2* __restrict__ out2v) {
    int wave = threadIdx.x >> 6;
    int lane = threadIdx.x & 63;
    int n = blockIdx.x * 4 + wave;
    if (n >= N) return;
    int lo = offsets[n], hi = offsets[n + 1];
    int slot = lane >> 4, li = lane & 15;
    float ad = ad2[n];
    float ax = 0.f, ay = 0.f, sumw = 0.f;
    for (int e = lo + slot; e < hi; e += 4) {
        int s = elist[e];
        float w = lrelu_exp(as2[s] + ad);
        float2 v = __half22float2(h2h[(size_t)s * 16 + li]);
        sumw += w;
        ax += w * v.x;
        ay += w * v.y;
    }
    ax += __shfl_xor(ax, 16, 64);  ax += __shfl_xor(ax, 32, 64);
    ay += __shfl_xor(ay, 16, 64);  ay += __shfl_xor(ay, 32, 64);
    sumw += __shfl_xor(sumw, 16, 64); sumw += __shfl_xor(sumw, 32, 64);
    if (slot == 0) {
        float inv = 1.f / (sumw + 1e-16f);
        float2 bv = b2v[li];
        float vx = ax * inv + bv.x;
        float vy = ay * inv + bv.y;
        vx = vx > 0.f ? vx : expm1f(vx);
        vy = vy > 0.f ? vy : expm1f(vy);
        out2v[(size_t)n * 16 + li] = make_float2(vx, vy);
    }
}

// ---- mean-pool per graph + MLP head ----
__global__ void k_pool(const float* __restrict__ out2, const int* __restrict__ batch,
                       int N, const float* __restrict__ Wh1, const float* __restrict__ bh1,
                       const float* __restrict__ Wh2, const float* __restrict__ bh2,
                       float* __restrict__ out) {
    int g = blockIdx.x;
    int t = threadIdx.x;
    __shared__ int sb[2];
    __shared__ float pooled[C2];
    __shared__ float red[256];
    if (t < 2) {
        int target = g + t;
        int lo = 0, hi = N;
        while (lo < hi) { int mid = (lo + hi) >> 1; if (batch[mid] < target) lo = mid + 1; else hi = mid; }
        sb[t] = lo;
    }
    __syncthreads();
    int lo = sb[0], hi = sb[1];
    int c = t & 31, grp = t >> 5;
    float part = 0.f;
    for (int n = lo + grp; n < hi; n += 8) part += out2[n * C2 + c];
    red[t] = part;
    __syncthreads();
    if (t < 128) red[t] += red[t + 128];
    __syncthreads();
    if (t < 64) red[t] += red[t + 64];
    __syncthreads();
    if (t < 32) {
        red[t] += red[t + 32];
        float cnt = (float)(hi - lo);
        pooled[t] = red[t] / fmaxf(cnt, 1.f);
    }
    __syncthreads();
    float hval = 0.f;
    if (t < HID) {
        float a = bh1[t];
#pragma unroll
        for (int cc = 0; cc < C2; ++cc) a += pooled[cc] * Wh1[cc * HID + t];
        hval = fmaxf(a, 0.f) * Wh2[t];
    }
    if (t < 64) {
        for (int o = 32; o > 0; o >>= 1) hval += __shfl_down(hval, o, 64);
        if (t == 0) out[g] = hval + bh2[0];
    }
}

extern "C" void kernel_launch(void* const* d_in, const int* in_sizes, int n_in,
                              void* d_out, int out_size, void* d_ws, size_t ws_size,
                              hipStream_t stream) {
    const float* x    = (const float*)d_in[0];
    const int*   ei   = (const int*)d_in[1];
    const int*   batch= (const int*)d_in[2];
    const float* W1   = (const float*)d_in[3];
    const float* aS1  = (const float*)d_in[4];
    const float* aD1  = (const float*)d_in[5];
    const float* b1   = (const float*)d_in[6];
    const float* W2   = (const float*)d_in[7];
    const float* aS2  = (const float*)d_in[8];
    const float* aD2  = (const float*)d_in[9];
    const float* b2   = (const float*)d_in[10];
    const float* Wh1  = (const float*)d_in[11];
    const float* bh1  = (const float*)d_in[12];
    const float* Wh2  = (const float*)d_in[13];
    const float* bh2  = (const float*)d_in[14];
    float* out = (float*)d_out;

    int N = in_sizes[2];
    int E = in_sizes[1] / 2;
    int M = E + N;
    int G = out_size;
    int nb = (N + SCAN_B - 1) / SCAN_B;

    char* p = (char*)d_ws;
    auto alloc = [&](size_t bytes) -> void* {
        void* r = (void*)p;
        p += (bytes + 255) & ~(size_t)255;
        return r;
    };
    __half2* h1h   = (__half2*)alloc((size_t)N * 64 * 4);   // N x 128 fp16
    __half2* out1h = (__half2*)alloc((size_t)N * 64 * 4);
    __half2* h2h   = (__half2*)alloc((size_t)N * 16 * 4);   // N x 32 fp16
    float* as1     = (float*)alloc((size_t)N * NH1 * 4);
    float* ad1     = (float*)alloc((size_t)N * NH1 * 4);
    float* as2     = (float*)alloc((size_t)N * 4);
    float* ad2     = (float*)alloc((size_t)N * 4);
    float* out2    = (float*)alloc((size_t)N * C2 * 4);
    int*   deg     = (int*)alloc((size_t)N * 4);
    int*   offsets = (int*)alloc((size_t)(N + 1) * 4);
    int*   cursor  = (int*)alloc((size_t)(N + 1) * 4);
    int*   elist   = (int*)alloc((size_t)M * 4);
    int*   tmp     = (int*)alloc((size_t)N * 4);
    int*   bsum    = (int*)alloc((size_t)nb * 4);
    int*   boff    = (int*)alloc((size_t)nb * 4);

    hipMemsetAsync(deg, 0, (size_t)N * 4, stream);
    k_deg<<<(M + 255) / 256, 256, 0, stream>>>(ei, E, N, deg);
    k_scan1<<<nb, SCAN_B, 0, stream>>>(deg, N, tmp, bsum);
    k_scan2<<<1, 1024, 0, stream>>>(bsum, nb, boff, offsets, N);
    k_scan3<<<nb, SCAN_B, 0, stream>>>(deg, tmp, boff, N, offsets, cursor);
    k_lin1<<<(N + 3) / 4, 256, 0, stream>>>(x, (const float2*)W1, (const float2*)aS1,
                                            (const float2*)aD1, N, h1h, as1, ad1);
    k_scatter<<<(M + 255) / 256, 256, 0, stream>>>(ei, E, N, cursor, elist);
    k_agg1<<<(N + 3) / 4, 256, 0, stream>>>(offsets, elist, as1, ad1, h1h,
                                            (const float2*)b1, N, out1h);
    k_lin2<<<(N + TN - 1) / TN, 256, 0, stream>>>(out1h, W2, aS2, aD2, N, h2h, as2, ad2);
    k_agg2<<<(N + 3) / 4, 256, 0, stream>>>(offsets, elist, as2, ad2, h2h,
                                            (const float2*)b2, N, (float2*)out2);
    k_pool<<<G, 256, 0, stream>>>(out2, batch, N, Wh1, bh1, Wh2, bh2, out);
}

// Round 4
// 423.413 us; speedup vs baseline: 1.5733x; 1.2243x over previous
//
#include <hip/hip_runtime.h>
#include <hip/hip_fp16.h>
#include <math.h>

#define IN_CH 16
#define HC1 128   // H1*C1
#define NH1 4
#define C2 32
#define HID 64
#define NEG 0.2f
#define SCAN_B 256
#define NPART 8

__device__ __forceinline__ float lrelu_exp(float z) {
    float lr = z > 0.f ? z : NEG * z;
    return expf(lr);
}

// ---- CSR build ----
__global__ void k_deg(const int* __restrict__ ei, int E, int N, int* __restrict__ deg) {
    int i = blockIdx.x * blockDim.x + threadIdx.x;
    int M = E + N;
    if (i >= M) return;
    int dst = (i < E) ? ei[E + i] : (i - E);
    atomicAdd(&deg[dst], 1);
}

__global__ void k_scan1(const int* __restrict__ deg, int N, int* __restrict__ tmp, int* __restrict__ bsum) {
    __shared__ int s[SCAN_B];
    int i = blockIdx.x * SCAN_B + threadIdx.x;
    int v = (i < N) ? deg[i] : 0;
    s[threadIdx.x] = v;
    __syncthreads();
    for (int o = 1; o < SCAN_B; o <<= 1) {
        int add = (threadIdx.x >= o) ? s[threadIdx.x - o] : 0;
        __syncthreads();
        s[threadIdx.x] += add;
        __syncthreads();
    }
    if (i < N) tmp[i] = s[threadIdx.x];
    if (threadIdx.x == SCAN_B - 1) bsum[blockIdx.x] = s[SCAN_B - 1];
}

__global__ void k_scan2(const int* __restrict__ bsum, int nb, int* __restrict__ boff,
                        int* __restrict__ offsets, int N) {
    __shared__ int s[1024];
    int t = threadIdx.x;
    int v = (t < nb) ? bsum[t] : 0;
    s[t] = v;
    __syncthreads();
    for (int o = 1; o < 1024; o <<= 1) {
        int add = (t >= o) ? s[t - o] : 0;
        __syncthreads();
        s[t] += add;
        __syncthreads();
    }
    if (t < nb) boff[t] = s[t] - v;
    if (t == nb - 1) offsets[N] = s[t];
}

__global__ void k_scan3(const int* __restrict__ deg, const int* __restrict__ tmp,
                        const int* __restrict__ boff, int N,
                        int* __restrict__ offsets, int* __restrict__ cursor) {
    int i = blockIdx.x * SCAN_B + threadIdx.x;
    if (i >= N) return;
    int excl = tmp[i] - deg[i] + boff[blockIdx.x];
    offsets[i] = excl;
    cursor[i] = excl;
}

// XCD-partitioned scatter: part p handles dst in [p*npp, (p+1)*npp).
// All elist/cursor lines for a dst range are written from one XCD -> L2 merge.
__global__ void k_scatter(const int* __restrict__ ei, int E, int N, int npp,
                          int* __restrict__ cursor, int* __restrict__ elist) {
    int part = blockIdx.x & (NPART - 1);
    int wg = blockIdx.x >> 3;
    int nwg = gridDim.x >> 3;
    int lo_n = part * npp;
    int hi_n = lo_n + npp;      // may exceed N; dst < N always
    int M = E + N;
    for (int i = wg * blockDim.x + threadIdx.x; i < M; i += nwg * blockDim.x) {
        int dst = (i < E) ? ei[E + i] : (i - E);
        if (dst >= lo_n && dst < hi_n) {
            int src = (i < E) ? ei[i] : dst;
            int pos = atomicAdd(&cursor[dst], 1);
            elist[pos] = src;
        }
    }
}

// ---- GAT1 linear + logits: one wave per node, 2 channels/lane ----
__global__ void k_lin1(const float* __restrict__ x, const float2* __restrict__ W1v,
                       const float2* __restrict__ att_s2, const float2* __restrict__ att_d2,
                       int N, __half2* __restrict__ h1h, float* __restrict__ as1, float* __restrict__ ad1) {
    int wave = threadIdx.x >> 6;
    int lane = threadIdx.x & 63;
    int n = blockIdx.x * 4 + wave;
    if (n >= N) return;
    float xv = x[n * IN_CH + (lane & 15)];
    float ax = 0.f, ay = 0.f;
#pragma unroll
    for (int k = 0; k < IN_CH; ++k) {
        float xk = __shfl(xv, k, 16);
        float2 w = W1v[k * 64 + lane];
        ax += xk * w.x;
        ay += xk * w.y;
    }
    h1h[(size_t)n * 64 + lane] = __floats2half2_rn(ax, ay);
    float2 s2 = att_s2[lane], d2 = att_d2[lane];
    float vs = ax * s2.x + ay * s2.y;
    float vd = ax * d2.x + ay * d2.y;
#pragma unroll
    for (int o = 1; o < 16; o <<= 1) {
        vs += __shfl_xor(vs, o, 64);
        vd += __shfl_xor(vd, o, 64);
    }
    if ((lane & 15) == 0) {
        as1[n * NH1 + (lane >> 4)] = vs;
        ad1[n * NH1 + (lane >> 4)] = vd;
    }
}

// ---- GAT1 aggregation: one wave per dst; 4 edge-slots x 16 lanes x float4 ----
// h1q: N rows of 16 float4 (128 fp16 ch). out1q: same layout.
__global__ void k_agg1(const int* __restrict__ offsets, const int* __restrict__ elist,
                       const float* __restrict__ as1, const float* __restrict__ ad1,
                       const float4* __restrict__ h1q, const float* __restrict__ b1,
                       int N, float4* __restrict__ out1q) {
    int wave = threadIdx.x >> 6;
    int lane = threadIdx.x & 63;
    int n = blockIdx.x * 4 + wave;
    if (n >= N) return;
    int slot = lane >> 4, chunk = lane & 15, head = chunk >> 2;
    int lo = offsets[n], hi = offsets[n + 1];
    float adh = ad1[n * NH1 + head];
    float acc[8];
#pragma unroll
    for (int j = 0; j < 8; ++j) acc[j] = 0.f;
    float sumw = 0.f;
#pragma unroll 2
    for (int e0 = lo; e0 < hi; e0 += 4) {
        int e = e0 + slot;
        bool ok = e < hi;
        int s = elist[ok ? e : lo];
        float w = ok ? lrelu_exp(as1[s * NH1 + head] + adh) : 0.f;
        float4 v = h1q[(size_t)s * 16 + chunk];
        const __half2* hv = (const __half2*)&v;
#pragma unroll
        for (int j = 0; j < 4; ++j) {
            float2 f = __half22float2(hv[j]);
            acc[2 * j] += w * f.x;
            acc[2 * j + 1] += w * f.y;
        }
        sumw += w;
    }
#pragma unroll
    for (int j = 0; j < 8; ++j) {
        acc[j] += __shfl_xor(acc[j], 16, 64);
        acc[j] += __shfl_xor(acc[j], 32, 64);
    }
    sumw += __shfl_xor(sumw, 16, 64);
    sumw += __shfl_xor(sumw, 32, 64);
    if (slot == 0) {
        float inv = 1.f / (sumw + 1e-16f);
        float4 ba = ((const float4*)b1)[2 * chunk];
        float4 bb = ((const float4*)b1)[2 * chunk + 1];
        float o[8];
        o[0] = acc[0] * inv + ba.x; o[1] = acc[1] * inv + ba.y;
        o[2] = acc[2] * inv + ba.z; o[3] = acc[3] * inv + ba.w;
        o[4] = acc[4] * inv + bb.x; o[5] = acc[5] * inv + bb.y;
        o[6] = acc[6] * inv + bb.z; o[7] = acc[7] * inv + bb.w;
#pragma unroll
        for (int j = 0; j < 8; ++j) o[j] = o[j] > 0.f ? o[j] : expm1f(o[j]);
        float4 pk;
        __half2* ph = (__half2*)&pk;
        ph[0] = __floats2half2_rn(o[0], o[1]);
        ph[1] = __floats2half2_rn(o[2], o[3]);
        ph[2] = __floats2half2_rn(o[4], o[5]);
        ph[3] = __floats2half2_rn(o[6], o[7]);
        out1q[(size_t)n * 16 + chunk] = pk;
    }
}

// ---- GAT2 linear: LDS-tiled GEMM [N,128](fp16) x [128,32] + logits ----
#define TN 64
__global__ void k_lin2(const __half2* __restrict__ out1h, const float* __restrict__ W2,
                       const float* __restrict__ att_s, const float* __restrict__ att_d,
                       int N, __half2* __restrict__ h2h, float* __restrict__ as2, float* __restrict__ ad2) {
    __shared__ float sx[TN][HC1 + 1];
    __shared__ float sw[HC1][C2];
    int t = threadIdx.x;  // 256
    int base = blockIdx.x * TN;
    int lim = (N - base) * HC1;
    for (int i = t * 4; i < HC1 * C2; i += 1024) {
        float4 v = *(const float4*)(W2 + i);
        sw[i >> 5][i & 31] = v.x;
        sw[i >> 5][(i & 31) + 1] = v.y;
        sw[i >> 5][(i & 31) + 2] = v.z;
        sw[i >> 5][(i & 31) + 3] = v.w;
    }
    for (int i = t * 4; i < TN * HC1; i += 1024) {
        float2 a = make_float2(0.f, 0.f), b = make_float2(0.f, 0.f);
        if (i < lim) {
            size_t idx = ((size_t)base * HC1 + i) >> 1;
            a = __half22float2(out1h[idx]);
            b = __half22float2(out1h[idx + 1]);
        }
        int nn = i >> 7, kk = i & 127;
        sx[nn][kk] = a.x; sx[nn][kk + 1] = a.y; sx[nn][kk + 2] = b.x; sx[nn][kk + 3] = b.y;
    }
    __syncthreads();
    int nloc = t >> 2;
    int c0 = (t & 3) * 8;
    float acc[8];
#pragma unroll
    for (int j = 0; j < 8; ++j) acc[j] = 0.f;
#pragma unroll 4
    for (int k = 0; k < HC1; ++k) {
        float xv = sx[nloc][k];
        float4 wa = *(float4*)&sw[k][c0];
        float4 wb = *(float4*)&sw[k][c0 + 4];
        acc[0] += xv * wa.x; acc[1] += xv * wa.y; acc[2] += xv * wa.z; acc[3] += xv * wa.w;
        acc[4] += xv * wb.x; acc[5] += xv * wb.y; acc[6] += xv * wb.z; acc[7] += xv * wb.w;
    }
    int n = base + nloc;
    if (n < N) {
#pragma unroll
        for (int j = 0; j < 4; ++j)
            h2h[(size_t)n * 16 + (c0 >> 1) + j] = __floats2half2_rn(acc[2 * j], acc[2 * j + 1]);
        float ps = 0.f, pd = 0.f;
#pragma unroll
        for (int j = 0; j < 8; ++j) {
            ps += acc[j] * att_s[c0 + j];
            pd += acc[j] * att_d[c0 + j];
        }
        ps += __shfl_down(ps, 1, 64); ps += __shfl_down(ps, 2, 64);
        pd += __shfl_down(pd, 1, 64); pd += __shfl_down(pd, 2, 64);
        if ((t & 3) == 0) { as2[n] = ps; ad2[n] = pd; }
    }
}

// ---- GAT2 aggregation: one wave per dst; 16 edge-slots x 4 lanes x float4 ----
// h2q: N rows of 4 float4 (32 fp16 ch).
__global__ void k_agg2(const int* __restrict__ offsets, const int* __restrict__ elist,
                       const float* __restrict__ as2, const float* __restrict__ ad2,
                       const float4* __restrict__ h2q, const float* __restrict__ b2,
                       int N, float* __restrict__ out2) {
    int wave = threadIdx.x >> 6;
    int lane = threadIdx.x & 63;
    int n = blockIdx.x * 4 + wave;
    if (n >= N) return;
    int slot = lane >> 2, chunk = lane & 3;
    int lo = offsets[n], hi = offsets[n + 1];
    float ad = ad2[n];
    float acc[8];
#pragma unroll
    for (int j = 0; j < 8; ++j) acc[j] = 0.f;
    float sumw = 0.f;
    for (int e0 = lo; e0 < hi; e0 += 16) {
        int e = e0 + slot;
        bool ok = e < hi;
        int s = elist[ok ? e : lo];
        float w = ok ? lrelu_exp(as2[s] + ad) : 0.f;
        float4 v = h2q[(size_t)s * 4 + chunk];
        const __half2* hv = (const __half2*)&v;
#pragma unroll
        for (int j = 0; j < 4; ++j) {
            float2 f = __half22float2(hv[j]);
            acc[2 * j] += w * f.x;
            acc[2 * j + 1] += w * f.y;
        }
        sumw += w;
    }
#pragma unroll
    for (int j = 0; j < 8; ++j) {
        acc[j] += __shfl_xor(acc[j], 4, 64);
        acc[j] += __shfl_xor(acc[j], 8, 64);
        acc[j] += __shfl_xor(acc[j], 16, 64);
        acc[j] += __shfl_xor(acc[j], 32, 64);
    }
    sumw += __shfl_xor(sumw, 4, 64);
    sumw += __shfl_xor(sumw, 8, 64);
    sumw += __shfl_xor(sumw, 16, 64);
    sumw += __shfl_xor(sumw, 32, 64);
    if (slot == 0) {
        float inv = 1.f / (sumw + 1e-16f);
        float4 ba = ((const float4*)b2)[2 * chunk];
        float4 bb = ((const float4*)b2)[2 * chunk + 1];
        float o[8];
        o[0] = acc[0] * inv + ba.x; o[1] = acc[1] * inv + ba.y;
        o[2] = acc[2] * inv + ba.z; o[3] = acc[3] * inv + ba.w;
        o[4] = acc[4] * inv + bb.x; o[5] = acc[5] * inv + bb.y;
        o[6] = acc[6] * inv + bb.z; o[7] = acc[7] * inv + bb.w;
#pragma unroll
        for (int j = 0; j < 8; ++j) o[j] = o[j] > 0.f ? o[j] : expm1f(o[j]);
        float* dst = out2 + (size_t)n * C2 + 8 * chunk;
        *(float4*)dst = make_float4(o[0], o[1], o[2], o[3]);
        *(float4*)(dst + 4) = make_float4(o[4], o[5], o[6], o[7]);
    }
}

// ---- mean-pool per graph + MLP head ----
__global__ void k_pool(const float* __restrict__ out2, const int* __restrict__ batch,
                       int N, const float* __restrict__ Wh1, const float* __restrict__ bh1,
                       const float* __restrict__ Wh2, const float* __restrict__ bh2,
                       float* __restrict__ out) {
    int g = blockIdx.x;
    int t = threadIdx.x;
    __shared__ int sb[2];
    __shared__ float pooled[C2];
    __shared__ float red[256];
    if (t < 2) {
        int target = g + t;
        int lo = 0, hi = N;
        while (lo < hi) { int mid = (lo + hi) >> 1; if (batch[mid] < target) lo = mid + 1; else hi = mid; }
        sb[t] = lo;
    }
    __syncthreads();
    int lo = sb[0], hi = sb[1];
    int c = t & 31, grp = t >> 5;
    float part = 0.f;
    for (int n = lo + grp; n < hi; n += 8) part += out2[n * C2 + c];
    red[t] = part;
    __syncthreads();
    if (t < 128) red[t] += red[t + 128];
    __syncthreads();
    if (t < 64) red[t] += red[t + 64];
    __syncthreads();
    if (t < 32) {
        red[t] += red[t + 32];
        float cnt = (float)(hi - lo);
        pooled[t] = red[t] / fmaxf(cnt, 1.f);
    }
    __syncthreads();
    float hval = 0.f;
    if (t < HID) {
        float a = bh1[t];
#pragma unroll
        for (int cc = 0; cc < C2; ++cc) a += pooled[cc] * Wh1[cc * HID + t];
        hval = fmaxf(a, 0.f) * Wh2[t];
    }
    if (t < 64) {
        for (int o = 32; o > 0; o >>= 1) hval += __shfl_down(hval, o, 64);
        if (t == 0) out[g] = hval + bh2[0];
    }
}

extern "C" void kernel_launch(void* const* d_in, const int* in_sizes, int n_in,
                              void* d_out, int out_size, void* d_ws, size_t ws_size,
                              hipStream_t stream) {
    const float* x    = (const float*)d_in[0];
    const int*   ei   = (const int*)d_in[1];
    const int*   batch= (const int*)d_in[2];
    const float* W1   = (const float*)d_in[3];
    const float* aS1  = (const float*)d_in[4];
    const float* aD1  = (const float*)d_in[5];
    const float* b1   = (const float*)d_in[6];
    const float* W2   = (const float*)d_in[7];
    const float* aS2  = (const float*)d_in[8];
    const float* aD2  = (const float*)d_in[9];
    const float* b2   = (const float*)d_in[10];
    const float* Wh1  = (const float*)d_in[11];
    const float* bh1  = (const float*)d_in[12];
    const float* Wh2  = (const float*)d_in[13];
    const float* bh2  = (const float*)d_in[14];
    float* out = (float*)d_out;

    int N = in_sizes[2];
    int E = in_sizes[1] / 2;
    int M = E + N;
    int G = out_size;
    int nb = (N + SCAN_B - 1) / SCAN_B;
    int npp = (N + NPART - 1) / NPART;

    char* p = (char*)d_ws;
    auto alloc = [&](size_t bytes) -> void* {
        void* r = (void*)p;
        p += (bytes + 255) & ~(size_t)255;
        return r;
    };
    __half2* h1h   = (__half2*)alloc((size_t)N * 64 * 4);   // N x 128 fp16
    __half2* out1h = (__half2*)alloc((size_t)N * 64 * 4);
    __half2* h2h   = (__half2*)alloc((size_t)N * 16 * 4);   // N x 32 fp16
    float* as1     = (float*)alloc((size_t)N * NH1 * 4);
    float* ad1     = (float*)alloc((size_t)N * NH1 * 4);
    float* as2     = (float*)alloc((size_t)N * 4);
    float* ad2     = (float*)alloc((size_t)N * 4);
    float* out2    = (float*)alloc((size_t)N * C2 * 4);
    int*   deg     = (int*)alloc((size_t)N * 4);
    int*   offsets = (int*)alloc((size_t)(N + 1) * 4);
    int*   cursor  = (int*)alloc((size_t)(N + 1) * 4);
    int*   elist   = (int*)alloc((size_t)M * 4);
    int*   tmp     = (int*)alloc((size_t)N * 4);
    int*   bsum    = (int*)alloc((size_t)nb * 4);
    int*   boff    = (int*)alloc((size_t)nb * 4);

    hipMemsetAsync(deg, 0, (size_t)N * 4, stream);
    k_deg<<<(M + 255) / 256, 256, 0, stream>>>(ei, E, N, deg);
    k_scan1<<<nb, SCAN_B, 0, stream>>>(deg, N, tmp, bsum);
    k_scan2<<<1, 1024, 0, stream>>>(bsum, nb, boff, offsets, N);
    k_scan3<<<nb, SCAN_B, 0, stream>>>(deg, tmp, boff, N, offsets, cursor);
    k_lin1<<<(N + 3) / 4, 256, 0, stream>>>(x, (const float2*)W1, (const float2*)aS1,
                                            (const float2*)aD1, N, h1h, as1, ad1);
    k_scatter<<<NPART * 128, 256, 0, stream>>>(ei, E, N, npp, cursor, elist);
    k_agg1<<<(N + 3) / 4, 256, 0, stream>>>(offsets, elist, as1, ad1,
                                            (const float4*)h1h, b1, N, (float4*)out1h);
    k_lin2<<<(N + TN - 1) / TN, 256, 0, stream>>>(out1h, W2, aS2, aD2, N, h2h, as2, ad2);
    k_agg2<<<(N + 3) / 4, 256, 0, stream>>>(offsets, elist, as2, ad2,
                                            (const float4*)h2h, b2, N, out2);
    k_pool<<<G, 256, 0, stream>>>(out2, batch, N, Wh1, bh1, Wh2, bh2, out);
}

// Round 5
// 403.073 us; speedup vs baseline: 1.6527x; 1.0505x over previous
//
#include <hip/hip_runtime.h>
#include <hip/hip_fp16.h>
#include <math.h>

#define IN_CH 16
#define HC1 128   // H1*C1
#define NH1 4
#define C2 32
#define HID 64
#define NEG 0.2f
#define SCAN_B 256
#define NPART 8

__device__ __forceinline__ float lrelu_exp(float z) {
    float lr = z > 0.f ? z : NEG * z;
    return expf(lr);
}

// ---- CSR build ----
// XCD-partitioned degree count: part p only counts dst in its range so the
// deg[] lines are touched by blocks on one XCD only (blockIdx%8 -> XCD RR).
__global__ void k_deg(const int* __restrict__ ei, int E, int N, int npp,
                      int* __restrict__ deg) {
    int part = blockIdx.x & (NPART - 1);
    int wg = blockIdx.x >> 3;
    int nwg = gridDim.x >> 3;
    int lo_n = part * npp;
    int hi_n = lo_n + npp;
    int M = E + N;
    for (int i = wg * blockDim.x + threadIdx.x; i < M; i += nwg * blockDim.x) {
        int dst = (i < E) ? ei[E + i] : (i - E);
        if (dst >= lo_n && dst < hi_n) atomicAdd(&deg[dst], 1);
    }
}

__global__ void k_scan1(const int* __restrict__ deg, int N, int* __restrict__ tmp, int* __restrict__ bsum) {
    __shared__ int s[SCAN_B];
    int i = blockIdx.x * SCAN_B + threadIdx.x;
    int v = (i < N) ? deg[i] : 0;
    s[threadIdx.x] = v;
    __syncthreads();
    for (int o = 1; o < SCAN_B; o <<= 1) {
        int add = (threadIdx.x >= o) ? s[threadIdx.x - o] : 0;
        __syncthreads();
        s[threadIdx.x] += add;
        __syncthreads();
    }
    if (i < N) tmp[i] = s[threadIdx.x];
    if (threadIdx.x == SCAN_B - 1) bsum[blockIdx.x] = s[SCAN_B - 1];
}

__global__ void k_scan2(const int* __restrict__ bsum, int nb, int* __restrict__ boff,
                        int* __restrict__ offsets, int N) {
    __shared__ int s[1024];
    int t = threadIdx.x;
    int v = (t < nb) ? bsum[t] : 0;
    s[t] = v;
    __syncthreads();
    for (int o = 1; o < 1024; o <<= 1) {
        int add = (t >= o) ? s[t - o] : 0;
        __syncthreads();
        s[t] += add;
        __syncthreads();
    }
    if (t < nb) boff[t] = s[t] - v;
    if (t == nb - 1) offsets[N] = s[t];
}

__global__ void k_scan3(const int* __restrict__ deg, const int* __restrict__ tmp,
                        const int* __restrict__ boff, int N,
                        int* __restrict__ offsets, int* __restrict__ cursor) {
    int i = blockIdx.x * SCAN_B + threadIdx.x;
    if (i >= N) return;
    int excl = tmp[i] - deg[i] + boff[blockIdx.x];
    offsets[i] = excl;
    cursor[i] = excl;
}

// XCD-partitioned scatter
__global__ void k_scatter(const int* __restrict__ ei, int E, int N, int npp,
                          int* __restrict__ cursor, int* __restrict__ elist) {
    int part = blockIdx.x & (NPART - 1);
    int wg = blockIdx.x >> 3;
    int nwg = gridDim.x >> 3;
    int lo_n = part * npp;
    int hi_n = lo_n + npp;
    int M = E + N;
    for (int i = wg * blockDim.x + threadIdx.x; i < M; i += nwg * blockDim.x) {
        int dst = (i < E) ? ei[E + i] : (i - E);
        if (dst >= lo_n && dst < hi_n) {
            int src = (i < E) ? ei[i] : dst;
            int pos = atomicAdd(&cursor[dst], 1);
            elist[pos] = src;
        }
    }
}

// ---- GAT1 linear + logits: one wave per node, 2 channels/lane ----
__global__ void k_lin1(const float* __restrict__ x, const float2* __restrict__ W1v,
                       const float2* __restrict__ att_s2, const float2* __restrict__ att_d2,
                       int N, __half2* __restrict__ h1h, float* __restrict__ as1, float* __restrict__ ad1) {
    int wave = threadIdx.x >> 6;
    int lane = threadIdx.x & 63;
    int n = blockIdx.x * 4 + wave;
    if (n >= N) return;
    float xv = x[n * IN_CH + (lane & 15)];
    float ax = 0.f, ay = 0.f;
#pragma unroll
    for (int k = 0; k < IN_CH; ++k) {
        float xk = __shfl(xv, k, 16);
        float2 w = W1v[k * 64 + lane];
        ax += xk * w.x;
        ay += xk * w.y;
    }
    h1h[(size_t)n * 64 + lane] = __floats2half2_rn(ax, ay);
    float2 s2 = att_s2[lane], d2 = att_d2[lane];
    float vs = ax * s2.x + ay * s2.y;
    float vd = ax * d2.x + ay * d2.y;
#pragma unroll
    for (int o = 1; o < 16; o <<= 1) {
        vs += __shfl_xor(vs, o, 64);
        vd += __shfl_xor(vd, o, 64);
    }
    if ((lane & 15) == 0) {
        as1[n * NH1 + (lane >> 4)] = vs;
        ad1[n * NH1 + (lane >> 4)] = vd;
    }
}

// ---- GAT1 aggregation: one wave per dst; 4 edge-slots x 16 lanes x float4,
//      16 edges in flight (manual 2x + unroll 2) ----
__global__ void k_agg1(const int* __restrict__ offsets, const int* __restrict__ elist,
                       const float* __restrict__ as1, const float* __restrict__ ad1,
                       const float4* __restrict__ h1q, const float* __restrict__ b1,
                       int N, float4* __restrict__ out1q) {
    int wave = threadIdx.x >> 6;
    int lane = threadIdx.x & 63;
    int n = blockIdx.x * 4 + wave;
    if (n >= N) return;
    int slot = lane >> 4, chunk = lane & 15, head = chunk >> 2;
    int lo = offsets[n], hi = offsets[n + 1];
    float adh = ad1[n * NH1 + head];
    float acc[8];
#pragma unroll
    for (int j = 0; j < 8; ++j) acc[j] = 0.f;
    float sumw = 0.f;
#pragma unroll 2
    for (int e0 = lo; e0 < hi; e0 += 8) {
        int eA = e0 + slot, eB = e0 + 4 + slot;
        bool okA = eA < hi, okB = eB < hi;
        int sA = elist[okA ? eA : lo];
        int sB = elist[okB ? eB : lo];
        float zA = as1[sA * NH1 + head];
        float zB = as1[sB * NH1 + head];
        float4 vA = h1q[(size_t)sA * 16 + chunk];
        float4 vB = h1q[(size_t)sB * 16 + chunk];
        float wA = okA ? lrelu_exp(zA + adh) : 0.f;
        float wB = okB ? lrelu_exp(zB + adh) : 0.f;
        const __half2* hA = (const __half2*)&vA;
        const __half2* hB = (const __half2*)&vB;
#pragma unroll
        for (int j = 0; j < 4; ++j) {
            float2 fA = __half22float2(hA[j]);
            float2 fB = __half22float2(hB[j]);
            acc[2 * j]     += wA * fA.x + wB * fB.x;
            acc[2 * j + 1] += wA * fA.y + wB * fB.y;
        }
        sumw += wA + wB;
    }
#pragma unroll
    for (int j = 0; j < 8; ++j) {
        acc[j] += __shfl_xor(acc[j], 16, 64);
        acc[j] += __shfl_xor(acc[j], 32, 64);
    }
    sumw += __shfl_xor(sumw, 16, 64);
    sumw += __shfl_xor(sumw, 32, 64);
    if (slot == 0) {
        float inv = 1.f / (sumw + 1e-16f);
        float4 ba = ((const float4*)b1)[2 * chunk];
        float4 bb = ((const float4*)b1)[2 * chunk + 1];
        float o[8];
        o[0] = acc[0] * inv + ba.x; o[1] = acc[1] * inv + ba.y;
        o[2] = acc[2] * inv + ba.z; o[3] = acc[3] * inv + ba.w;
        o[4] = acc[4] * inv + bb.x; o[5] = acc[5] * inv + bb.y;
        o[6] = acc[6] * inv + bb.z; o[7] = acc[7] * inv + bb.w;
#pragma unroll
        for (int j = 0; j < 8; ++j) o[j] = o[j] > 0.f ? o[j] : expm1f(o[j]);
        float4 pk;
        __half2* ph = (__half2*)&pk;
        ph[0] = __floats2half2_rn(o[0], o[1]);
        ph[1] = __floats2half2_rn(o[2], o[3]);
        ph[2] = __floats2half2_rn(o[4], o[5]);
        ph[3] = __floats2half2_rn(o[6], o[7]);
        out1q[(size_t)n * 16 + chunk] = pk;
    }
}

// ---- GAT2 linear: LDS-tiled GEMM [N,128](fp16) x [128,32] + logits ----
#define TN 64
__global__ void k_lin2(const __half2* __restrict__ out1h, const float* __restrict__ W2,
                       const float* __restrict__ att_s, const float* __restrict__ att_d,
                       int N, __half2* __restrict__ h2h, float* __restrict__ as2, float* __restrict__ ad2) {
    __shared__ float sx[TN][HC1 + 1];
    __shared__ float sw[HC1][C2];
    int t = threadIdx.x;  // 256
    int base = blockIdx.x * TN;
    int lim = (N - base) * HC1;
    for (int i = t * 4; i < HC1 * C2; i += 1024) {
        float4 v = *(const float4*)(W2 + i);
        sw[i >> 5][i & 31] = v.x;
        sw[i >> 5][(i & 31) + 1] = v.y;
        sw[i >> 5][(i & 31) + 2] = v.z;
        sw[i >> 5][(i & 31) + 3] = v.w;
    }
    for (int i = t * 4; i < TN * HC1; i += 1024) {
        float2 a = make_float2(0.f, 0.f), b = make_float2(0.f, 0.f);
        if (i < lim) {
            size_t idx = ((size_t)base * HC1 + i) >> 1;
            a = __half22float2(out1h[idx]);
            b = __half22float2(out1h[idx + 1]);
        }
        int nn = i >> 7, kk = i & 127;
        sx[nn][kk] = a.x; sx[nn][kk + 1] = a.y; sx[nn][kk + 2] = b.x; sx[nn][kk + 3] = b.y;
    }
    __syncthreads();
    int nloc = t >> 2;
    int c0 = (t & 3) * 8;
    float acc[8];
#pragma unroll
    for (int j = 0; j < 8; ++j) acc[j] = 0.f;
#pragma unroll 4
    for (int k = 0; k < HC1; ++k) {
        float xv = sx[nloc][k];
        float4 wa = *(float4*)&sw[k][c0];
        float4 wb = *(float4*)&sw[k][c0 + 4];
        acc[0] += xv * wa.x; acc[1] += xv * wa.y; acc[2] += xv * wa.z; acc[3] += xv * wa.w;
        acc[4] += xv * wb.x; acc[5] += xv * wb.y; acc[6] += xv * wb.z; acc[7] += xv * wb.w;
    }
    int n = base + nloc;
    if (n < N) {
#pragma unroll
        for (int j = 0; j < 4; ++j)
            h2h[(size_t)n * 16 + (c0 >> 1) + j] = __floats2half2_rn(acc[2 * j], acc[2 * j + 1]);
        float ps = 0.f, pd = 0.f;
#pragma unroll
        for (int j = 0; j < 8; ++j) {
            ps += acc[j] * att_s[c0 + j];
            pd += acc[j] * att_d[c0 + j];
        }
        ps += __shfl_down(ps, 1, 64); ps += __shfl_down(ps, 2, 64);
        pd += __shfl_down(pd, 1, 64); pd += __shfl_down(pd, 2, 64);
        if ((t & 3) == 0) { as2[n] = ps; ad2[n] = pd; }
    }
}

// ---- GAT2 aggregation: one wave per dst; 16 edge-slots x 4 lanes x float4,
//      32 edges in flight (manual 2x) ----
__global__ void k_agg2(const int* __restrict__ offsets, const int* __restrict__ elist,
                       const float* __restrict__ as2, const float* __restrict__ ad2,
                       const float4* __restrict__ h2q, const float* __restrict__ b2,
                       int N, float* __restrict__ out2) {
    int wave = threadIdx.x >> 6;
    int lane = threadIdx.x & 63;
    int n = blockIdx.x * 4 + wave;
    if (n >= N) return;
    int slot = lane >> 2, chunk = lane & 3;
    int lo = offsets[n], hi = offsets[n + 1];
    float ad = ad2[n];
    float acc[8];
#pragma unroll
    for (int j = 0; j < 8; ++j) acc[j] = 0.f;
    float sumw = 0.f;
    for (int e0 = lo; e0 < hi; e0 += 32) {
        int eA = e0 + slot, eB = e0 + 16 + slot;
        bool okA = eA < hi, okB = eB < hi;
        int sA = elist[okA ? eA : lo];
        int sB = elist[okB ? eB : lo];
        float zA = as2[sA];
        float zB = as2[sB];
        float4 vA = h2q[(size_t)sA * 4 + chunk];
        float4 vB = h2q[(size_t)sB * 4 + chunk];
        float wA = okA ? lrelu_exp(zA + ad) : 0.f;
        float wB = okB ? lrelu_exp(zB + ad) : 0.f;
        const __half2* hA = (const __half2*)&vA;
        const __half2* hB = (const __half2*)&vB;
#pragma unroll
        for (int j = 0; j < 4; ++j) {
            float2 fA = __half22float2(hA[j]);
            float2 fB = __half22float2(hB[j]);
            acc[2 * j]     += wA * fA.x + wB * fB.x;
            acc[2 * j + 1] += wA * fA.y + wB * fB.y;
        }
        sumw += wA + wB;
    }
#pragma unroll
    for (int j = 0; j < 8; ++j) {
        acc[j] += __shfl_xor(acc[j], 4, 64);
        acc[j] += __shfl_xor(acc[j], 8, 64);
        acc[j] += __shfl_xor(acc[j], 16, 64);
        acc[j] += __shfl_xor(acc[j], 32, 64);
    }
    sumw += __shfl_xor(sumw, 4, 64);
    sumw += __shfl_xor(sumw, 8, 64);
    sumw += __shfl_xor(sumw, 16, 64);
    sumw += __shfl_xor(sumw, 32, 64);
    if (slot == 0) {
        float inv = 1.f / (sumw + 1e-16f);
        float4 ba = ((const float4*)b2)[2 * chunk];
        float4 bb = ((const float4*)b2)[2 * chunk + 1];
        float o[8];
        o[0] = acc[0] * inv + ba.x; o[1] = acc[1] * inv + ba.y;
        o[2] = acc[2] * inv + ba.z; o[3] = acc[3] * inv + ba.w;
        o[4] = acc[4] * inv + bb.x; o[5] = acc[5] * inv + bb.y;
        o[6] = acc[6] * inv + bb.z; o[7] = acc[7] * inv + bb.w;
#pragma unroll
        for (int j = 0; j < 8; ++j) o[j] = o[j] > 0.f ? o[j] : expm1f(o[j]);
        float* dst = out2 + (size_t)n * C2 + 8 * chunk;
        *(float4*)dst = make_float4(o[0], o[1], o[2], o[3]);
        *(float4*)(dst + 4) = make_float4(o[4], o[5], o[6], o[7]);
    }
}

// ---- mean-pool per graph + MLP head ----
__global__ void k_pool(const float* __restrict__ out2, const int* __restrict__ batch,
                       int N, const float* __restrict__ Wh1, const float* __restrict__ bh1,
                       const float* __restrict__ Wh2, const float* __restrict__ bh2,
                       float* __restrict__ out) {
    int g = blockIdx.x;
    int t = threadIdx.x;
    __shared__ int sb[2];
    __shared__ float pooled[C2];
    __shared__ float red[256];
    if (t < 2) {
        int target = g + t;
        int lo = 0, hi = N;
        while (lo < hi) { int mid = (lo + hi) >> 1; if (batch[mid] < target) lo = mid + 1; else hi = mid; }
        sb[t] = lo;
    }
    __syncthreads();
    int lo = sb[0], hi = sb[1];
    int c = t & 31, grp = t >> 5;
    float part = 0.f;
    for (int n = lo + grp; n < hi; n += 8) part += out2[n * C2 + c];
    red[t] = part;
    __syncthreads();
    if (t < 128) red[t] += red[t + 128];
    __syncthreads();
    if (t < 64) red[t] += red[t + 64];
    __syncthreads();
    if (t < 32) {
        red[t] += red[t + 32];
        float cnt = (float)(hi - lo);
        pooled[t] = red[t] / fmaxf(cnt, 1.f);
    }
    __syncthreads();
    float hval = 0.f;
    if (t < HID) {
        float a = bh1[t];
#pragma unroll
        for (int cc = 0; cc < C2; ++cc) a += pooled[cc] * Wh1[cc * HID + t];
        hval = fmaxf(a, 0.f) * Wh2[t];
    }
    if (t < 64) {
        for (int o = 32; o > 0; o >>= 1) hval += __shfl_down(hval, o, 64);
        if (t == 0) out[g] = hval + bh2[0];
    }
}

extern "C" void kernel_launch(void* const* d_in, const int* in_sizes, int n_in,
                              void* d_out, int out_size, void* d_ws, size_t ws_size,
                              hipStream_t stream) {
    const float* x    = (const float*)d_in[0];
    const int*   ei   = (const int*)d_in[1];
    const int*   batch= (const int*)d_in[2];
    const float* W1   = (const float*)d_in[3];
    const float* aS1  = (const float*)d_in[4];
    const float* aD1  = (const float*)d_in[5];
    const float* b1   = (const float*)d_in[6];
    const float* W2   = (const float*)d_in[7];
    const float* aS2  = (const float*)d_in[8];
    const float* aD2  = (const float*)d_in[9];
    const float* b2   = (const float*)d_in[10];
    const float* Wh1  = (const float*)d_in[11];
    const float* bh1  = (const float*)d_in[12];
    const float* Wh2  = (const float*)d_in[13];
    const float* bh2  = (const float*)d_in[14];
    float* out = (float*)d_out;

    int N = in_sizes[2];
    int E = in_sizes[1] / 2;
    int M = E + N;
    int G = out_size;
    int nb = (N + SCAN_B - 1) / SCAN_B;
    int npp = (N + NPART - 1) / NPART;

    char* p = (char*)d_ws;
    auto alloc = [&](size_t bytes) -> void* {
        void* r = (void*)p;
        p += (bytes + 255) & ~(size_t)255;
        return r;
    };
    __half2* h1h   = (__half2*)alloc((size_t)N * 64 * 4);   // N x 128 fp16
    __half2* out1h = (__half2*)alloc((size_t)N * 64 * 4);
    __half2* h2h   = (__half2*)alloc((size_t)N * 16 * 4);   // N x 32 fp16
    float* as1     = (float*)alloc((size_t)N * NH1 * 4);
    float* ad1     = (float*)alloc((size_t)N * NH1 * 4);
    float* as2     = (float*)alloc((size_t)N * 4);
    float* ad2     = (float*)alloc((size_t)N * 4);
    float* out2    = (float*)alloc((size_t)N * C2 * 4);
    int*   deg     = (int*)alloc((size_t)N * 4);
    int*   offsets = (int*)alloc((size_t)(N + 1) * 4);
    int*   cursor  = (int*)alloc((size_t)(N + 1) * 4);
    int*   elist   = (int*)alloc((size_t)M * 4);
    int*   tmp     = (int*)alloc((size_t)N * 4);
    int*   bsum    = (int*)alloc((size_t)nb * 4);
    int*   boff    = (int*)alloc((size_t)nb * 4);

    hipMemsetAsync(deg, 0, (size_t)N * 4, stream);
    k_deg<<<NPART * 128, 256, 0, stream>>>(ei, E, N, npp, deg);
    k_scan1<<<nb, SCAN_B, 0, stream>>>(deg, N, tmp, bsum);
    k_scan2<<<1, 1024, 0, stream>>>(bsum, nb, boff, offsets, N);
    k_scan3<<<nb, SCAN_B, 0, stream>>>(deg, tmp, boff, N, offsets, cursor);
    k_lin1<<<(N + 3) / 4, 256, 0, stream>>>(x, (const float2*)W1, (const float2*)aS1,
                                            (const float2*)aD1, N, h1h, as1, ad1);
    k_scatter<<<NPART * 128, 256, 0, stream>>>(ei, E, N, npp, cursor, elist);
    k_agg1<<<(N + 3) / 4, 256, 0, stream>>>(offsets, elist, as1, ad1,
                                            (const float4*)h1h, b1, N, (float4*)out1h);
    k_lin2<<<(N + TN - 1) / TN, 256, 0, stream>>>(out1h, W2, aS2, aD2, N, h2h, as2, ad2);
    k_agg2<<<(N + 3) / 4, 256, 0, stream>>>(offsets, elist, as2, ad2,
                                            (const float4*)h2h, b2, N, out2);
    k_pool<<<G, 256, 0, stream>>>(out2, batch, N, Wh1, bh1, Wh2, bh2, out);
}